// Round 14
// baseline (238.671 us; speedup 1.0000x reference)
//
#include <hip/hip_runtime.h>
#include <math.h>

#define BB  2
#define SS  2048
#define DD  1024
#define HH  16
#define DHH 64
#define MM  (BB * SS)   // 4096 rows

typedef float f32x4 __attribute__((ext_vector_type(4)));
typedef short s16x8 __attribute__((ext_vector_type(8)));

__device__ __forceinline__ unsigned short f2b(float f) {
    union { float f; unsigned u; } v; v.f = f;
    unsigned r = v.u + 0x7fffu + ((v.u >> 16) & 1u);
    return (unsigned short)(r >> 16);
}
__device__ __forceinline__ float b2f(unsigned short u) {
    union { unsigned u; float f; } v; v.u = ((unsigned)u) << 16;
    return v.f;
}
// pack 2 f32 -> 2 bf16 (low=first), RNE
__device__ __forceinline__ unsigned cvtpk(float lo, float hi) {
    unsigned r;
    asm("v_cvt_pk_bf16_f32 %0, %1, %2" : "=v"(r) : "v"(lo), "v"(hi));
    return r;
}

typedef __attribute__((address_space(1))) void gv_t;
typedef __attribute__((address_space(3))) void lv_t;
__device__ __forceinline__ void gld16(const void* g, void* l) {
    __builtin_amdgcn_global_load_lds((gv_t*)(void*)g, (lv_t*)l, 16, 0, 0);
}

__device__ __forceinline__ int sigma(int row) { return (row + (row >> 3)) & 7; }
// 64-col bf16 tile swizzle (16B-chunk XOR)
__device__ __forceinline__ int sidx(int row, int col) {
    return row * 64 + (col ^ (sigma(row) << 3));
}

// ---------------------------------------------------------------------------
// bf16 MFMA GEMM (m97 structure, 16x16x32 core — round-7-verified):
// C = A @ B^T + bias (+res)(relu).  Tile 128 x BN (BN = 128 or 64).
// VS=1 (BN=128 only): QKV mode — cols<2048 -> out, cols>=2048 -> vt[b][h][dh][s].
// RES: 0 none, 1 fp32, 2 bf16.  OUTF: 1 fp32 out, 0 bf16 out.
// ---------------------------------------------------------------------------
template <int RELU, int RES, int OUTF, int VS, int BN>
__global__ __launch_bounds__(256)
void mgemm(const unsigned short* __restrict__ A, const unsigned short* __restrict__ B,
           const float* __restrict__ bias, const void* __restrict__ res,
           void* __restrict__ out, unsigned short* __restrict__ vt,
           int M, int N, int K, int outN)
{
    __shared__ short As[128 * 64];
    __shared__ short Bs[BN * 64];

    const int tid  = threadIdx.x;
    const int wave = tid >> 6, lane = tid & 63;
    const int bm = blockIdx.y * 128, bn = blockIdx.x * BN;
    const int srow = tid >> 3;
    const int scol = (tid & 7) * 8;
    const int fr = lane & 15;
    const int fk = (lane >> 4) * 8;
    const int wrow = (BN == 128) ? (wave >> 1) * 64 : wave * 32;
    const int wcol = (BN == 128) ? (wave & 1) * 64 : 0;
    constexpr int MI = (BN == 128) ? 4 : 2;   // m-frags per wave

    f32x4 acc[MI][4];
#pragma unroll
    for (int i = 0; i < MI; ++i)
#pragma unroll
        for (int j = 0; j < 4; ++j) acc[i][j] = (f32x4){0.f, 0.f, 0.f, 0.f};

    for (int k0 = 0; k0 < K; k0 += 64) {
#pragma unroll
        for (int it = 0; it < 4; ++it)
            gld16(&A[(size_t)(bm + it * 32 + srow) * K + k0 + scol],
                  &As[it * 2048 + wave * 512]);
#pragma unroll
        for (int it = 0; it < BN / 32; ++it)
            gld16(&B[(size_t)(bn + it * 32 + srow) * K + k0 + scol],
                  &Bs[it * 2048 + wave * 512]);
        __syncthreads();

#pragma unroll
        for (int kk = 0; kk < 2; ++kk) {
            s16x8 af[MI], bf[4];
#pragma unroll
            for (int i = 0; i < MI; ++i)
                af[i] = *(const s16x8*)&As[(wrow + i * 16 + fr) * 64 + kk * 32 + fk];
#pragma unroll
            for (int j = 0; j < 4; ++j)
                bf[j] = *(const s16x8*)&Bs[(wcol + j * 16 + fr) * 64 + kk * 32 + fk];
#pragma unroll
            for (int i = 0; i < MI; ++i)
#pragma unroll
                for (int j = 0; j < 4; ++j)
                    acc[i][j] = __builtin_amdgcn_mfma_f32_16x16x32_bf16(
                        af[i], bf[j], acc[i][j], 0, 0, 0);
        }
        __syncthreads();
    }

    const int r0 = bm + wrow + (lane >> 4) * 4;
    const int c0 = bn + wcol + (lane & 15);
    const float* resf          = (const float*)res;
    const unsigned short* resh = (const unsigned short*)res;
    float* outf          = (float*)out;
    unsigned short* outh = (unsigned short*)out;

    if (VS == 1 && bn >= 2048) {
#pragma unroll
        for (int i = 0; i < MI; ++i)
#pragma unroll
            for (int j = 0; j < 4; ++j) {
                const int col = c0 + j * 16;
                const int hh = (col >> 6) & 15, dh = col & 63;
                const float bcol = bias[col];
#pragma unroll
                for (int r = 0; r < 4; ++r) {
                    const int row = r0 + i * 16 + r;
                    const int bb = row >> 11, s = row & 2047;
                    vt[(size_t)(((bb * 16 + hh) * 64) + dh) * 2048 + s] =
                        f2b(acc[i][j][r] + bcol);
                }
            }
        return;
    }

#pragma unroll
    for (int i = 0; i < MI; ++i)
#pragma unroll
        for (int j = 0; j < 4; ++j) {
            const int col = c0 + j * 16;
            const float bcol = bias[col];
#pragma unroll
            for (int r = 0; r < 4; ++r) {
                const int row = r0 + i * 16 + r;
                float v = acc[i][j][r] + bcol;
                if (RES == 1) v += resf[(size_t)row * outN + col];
                if (RES == 2) v += b2f(resh[(size_t)row * outN + col]);
                if (RELU)     v = fmaxf(v, 0.f);
                if (OUTF) outf[(size_t)row * outN + col] = v;
                else      outh[(size_t)row * outN + col] = f2b(v);
            }
        }
}

// ---------------------------------------------------------------------------
// Fused prep: x->bf16, 6 weight transposes (fp32[K][N] -> bf16[N][K]), bias pack.
// ---------------------------------------------------------------------------
__global__ __launch_bounds__(256)
void prep(const float* __restrict__ x,
          const float* __restrict__ wq, const float* __restrict__ wk,
          const float* __restrict__ wv, const float* __restrict__ wo,
          const float* __restrict__ w1, const float* __restrict__ w2,
          const float* __restrict__ bq, const float* __restrict__ bk,
          const float* __restrict__ bv,
          unsigned short* __restrict__ xb, unsigned short* __restrict__ wqkvT,
          unsigned short* __restrict__ woT, unsigned short* __restrict__ w1T,
          unsigned short* __restrict__ w2T, float* __restrict__ bqkv)
{
    __shared__ float T[64][65];
    const int tid = threadIdx.x;
    int bid = blockIdx.x;

    if (bid < 4096) {   // x -> bf16
        const int i = bid * 256 + tid;
        const float4 v = ((const float4*)x)[i];
        ushort4 o4;
        o4.x = f2b(v.x); o4.y = f2b(v.y); o4.z = f2b(v.z); o4.w = f2b(v.w);
        ((ushort4*)xb)[i] = o4;
        return;
    }
    bid -= 4096;

    if (bid >= 2048) {  // bias pack, 12 blocks
        const int i = (bid - 2048) * 256 + tid;
        if (i < 1024) bqkv[i] = bq[i];
        else if (i < 2048) bqkv[i] = bk[i - 1024];
        else if (i < 3072) bqkv[i] = bv[i - 2048];
        return;
    }

    const float* src; unsigned short* dst; int K, N, nbx, sub;
    if (bid < 256)       { src = wq; dst = wqkvT;               K = 1024; N = 1024; nbx = 16; sub = bid; }
    else if (bid < 512)  { src = wk; dst = wqkvT + 1024 * 1024; K = 1024; N = 1024; nbx = 16; sub = bid - 256; }
    else if (bid < 768)  { src = wv; dst = wqkvT + 2048 * 1024; K = 1024; N = 1024; nbx = 16; sub = bid - 512; }
    else if (bid < 1024) { src = wo; dst = woT;                 K = 1024; N = 1024; nbx = 16; sub = bid - 768; }
    else if (bid < 1536) { src = w1; dst = w1T;                 K = 1024; N = 2048; nbx = 32; sub = bid - 1024; }
    else                 { src = w2; dst = w2T;                 K = 2048; N = 1024; nbx = 16; sub = bid - 1536; }

    const int n0 = (sub % nbx) * 64, k0 = (sub / nbx) * 64;
    const int c = tid & 63, rb = tid >> 6;
#pragma unroll
    for (int it = 0; it < 16; ++it) {
        const int r = it * 4 + rb;
        T[r][c] = src[(size_t)(k0 + r) * N + n0 + c];
    }
    __syncthreads();
#pragma unroll
    for (int it = 0; it < 16; ++it) {
        const int r = it * 4 + rb;
        dst[(size_t)(n0 + r) * K + k0 + c] = f2b(T[c][r]);
    }
}

// ---------------------------------------------------------------------------
// MFMA flash attention, split-K over 2 key-halves. Inner loop = round-7-
// verified (FROZEN). Block = (128 q-rows, head, b*2+half); 8 waves.
// Each block sweeps 16 of 32 key tiles, writes normalized half-O (bf16) to
// part[half] and per-row log2-weight w = m + log2(accS) to scl.
// ---------------------------------------------------------------------------
__global__ __launch_bounds__(512)
void attn_mfma(const unsigned short* __restrict__ qk,
               const unsigned short* __restrict__ vt,
               const int* __restrict__ mask,
               unsigned short* __restrict__ part,   // [2][4096][1024] bf16
               float* __restrict__ scl)             // [2][4096][16]
{
    const int b = blockIdx.z >> 1, half = blockIdx.z & 1;
    const int h = blockIdx.y, q0 = blockIdx.x * 128;
    __shared__ unsigned short QP[8192];   // 128x64 Q; after frag load: P strips
    __shared__ unsigned short Ks[4096];   // 64x64
    __shared__ unsigned short Vs[4096];   // 64x64 (rows=dh, cols=kv)
    __shared__ float maskf[64];
    const int tid = threadIdx.x, wave = tid >> 6, lane = tid & 63;
    const int grp = lane >> 4, l16 = lane & 15;

    const size_t qkbase = (size_t)(b * SS) * 2048 + h * DHH;
    const size_t vbase  = (size_t)((b * HH + h) * 64) * 2048;
    const float SC = 0.18033688f;          // 0.125 * log2(e)
    const float MNEG = -1.442695e9f;       // -1e9 * log2(e)

    // ---- stage Q (once) ----
#pragma unroll
    for (int it = 0; it < 2; ++it) {
        const int slot = it * 512 + tid;
        const int row = slot >> 3, dhb = slot & 7;
        const int src = (dhb ^ sigma(row)) * 8;
        gld16(&qk[qkbase + (size_t)(q0 + row) * 2048 + src],
              &QP[it * 4096 + wave * 512]);
    }
    const int krow = tid >> 3, kdhb = tid & 7;
    const int ksrc = (kdhb ^ sigma(krow)) * 8;
    __syncthreads();
    const int prow = wave * 16 + l16;     // this lane's q row (LDS row index)
    const s16x8 aq0 = *(const s16x8*)&QP[sidx(prow, grp * 8)];
    const s16x8 aq1 = *(const s16x8*)&QP[sidx(prow, 32 + grp * 8)];

    const s16x8 ones = {(short)0x3F80, (short)0x3F80, (short)0x3F80, (short)0x3F80,
                        (short)0x3F80, (short)0x3F80, (short)0x3F80, (short)0x3F80};

    f32x4 accO[4];
#pragma unroll
    for (int j = 0; j < 4; ++j) accO[j] = (f32x4){0.f, 0.f, 0.f, 0.f};
    f32x4 accS = (f32x4){0.f, 0.f, 0.f, 0.f};
    float mrow = -1e30f;                   // running max for q = l16 (scalar)

    const int kt0 = half * (SS / 128);     // 16 tiles per half
    for (int kt = kt0; kt < kt0 + SS / 128; ++kt) {
        const int kv0 = kt * 64;
        __syncthreads();   // prev tile reads done
        gld16(&qk[qkbase + (size_t)(kv0 + krow) * 2048 + 1024 + ksrc], &Ks[wave * 512]);
        gld16(&vt[vbase + (size_t)krow * 2048 + kv0 + ksrc],           &Vs[wave * 512]);
        if (tid < 64) maskf[tid] = mask[b * SS + kv0 + tid] ? 0.f : MNEG;
        __syncthreads();   // staging + maskf visible

        // ---- QK^T (swapped: K is A, Q is B) ----
        f32x4 sv[4];
        __builtin_amdgcn_s_setprio(1);
#pragma unroll
        for (int j = 0; j < 4; ++j) {
            const s16x8 bk0 = *(const s16x8*)&Ks[sidx(j * 16 + l16, grp * 8)];
            const s16x8 bk1 = *(const s16x8*)&Ks[sidx(j * 16 + l16, 32 + grp * 8)];
            f32x4 z = (f32x4){0.f, 0.f, 0.f, 0.f};
            z = __builtin_amdgcn_mfma_f32_16x16x32_bf16(bk0, aq0, z, 0, 0, 0);
            z = __builtin_amdgcn_mfma_f32_16x16x32_bf16(bk1, aq1, z, 0, 0, 0);
            sv[j] = z;   // sv[j][r] = S[q=l16][k = j*16 + grp*4 + r]
        }
        __builtin_amdgcn_s_setprio(0);
#pragma unroll
        for (int j = 0; j < 4; ++j) {
            const float4 mv = *(const float4*)&maskf[j * 16 + grp * 4];
            sv[j][0] = sv[j][0] * SC + mv.x;
            sv[j][1] = sv[j][1] * SC + mv.y;
            sv[j][2] = sv[j][2] * SC + mv.z;
            sv[j][3] = sv[j][3] * SC + mv.w;
        }

        // ---- softmax for q=l16: lane-local max + 2 shfl ----
        float mx = -1e30f;
#pragma unroll
        for (int j = 0; j < 4; ++j)
#pragma unroll
            for (int r = 0; r < 4; ++r) mx = fmaxf(mx, sv[j][r]);
        mx = fmaxf(mx, __shfl_xor(mx, 16));
        mx = fmaxf(mx, __shfl_xor(mx, 32));

        if (!__all(mx <= mrow + 8.f)) {
            const float mnew = fmaxf(mrow, mx);
            const float corrq = __builtin_amdgcn_exp2f(mrow - mnew);  // for q=l16
            mrow = mnew;
            float cr[4];   // corr for q = grp*4+r (PV accumulator layout)
#pragma unroll
            for (int r = 0; r < 4; ++r) cr[r] = __shfl(corrq, grp * 4 + r);
#pragma unroll
            for (int r = 0; r < 4; ++r) {
                accS[r] *= cr[r];
#pragma unroll
                for (int j = 0; j < 4; ++j) accO[j][r] *= cr[r];
            }
        }

        // ---- P = exp2, pack to bf16, write wave-private strip ----
#pragma unroll
        for (int j = 0; j < 4; ++j) {
            const float p0 = __builtin_amdgcn_exp2f(sv[j][0] - mrow);
            const float p1 = __builtin_amdgcn_exp2f(sv[j][1] - mrow);
            const float p2 = __builtin_amdgcn_exp2f(sv[j][2] - mrow);
            const float p3 = __builtin_amdgcn_exp2f(sv[j][3] - mrow);
            *(unsigned*)&QP[sidx(prow, j * 16 + grp * 4)]     = cvtpk(p0, p1);
            *(unsigned*)&QP[sidx(prow, j * 16 + grp * 4 + 2)] = cvtpk(p2, p3);
        }

        // ---- PV + ones row-sum ----
        const s16x8 pa0 = *(const s16x8*)&QP[sidx(prow, grp * 8)];
        const s16x8 pa1 = *(const s16x8*)&QP[sidx(prow, 32 + grp * 8)];
        __builtin_amdgcn_s_setprio(1);
        accS = __builtin_amdgcn_mfma_f32_16x16x32_bf16(pa0, ones, accS, 0, 0, 0);
        accS = __builtin_amdgcn_mfma_f32_16x16x32_bf16(pa1, ones, accS, 0, 0, 0);
#pragma unroll
        for (int j = 0; j < 4; ++j) {
            const s16x8 vb0 = *(const s16x8*)&Vs[sidx(j * 16 + l16, grp * 8)];
            const s16x8 vb1 = *(const s16x8*)&Vs[sidx(j * 16 + l16, 32 + grp * 8)];
            accO[j] = __builtin_amdgcn_mfma_f32_16x16x32_bf16(pa0, vb0, accO[j], 0, 0, 0);
            accO[j] = __builtin_amdgcn_mfma_f32_16x16x32_bf16(pa1, vb1, accO[j], 0, 0, 0);
        }
        __builtin_amdgcn_s_setprio(0);
    }

    // ---- epilogue: normalized half-O (bf16) + per-row log2 weight ----
    unsigned short* po = part + (size_t)half * MM * DD;
#pragma unroll
    for (int r = 0; r < 4; ++r) {
        const float mr = __shfl(mrow, grp * 4 + r);   // max for q = grp*4+r
        const float inv = 1.0f / accS[r];
        const int row = q0 + wave * 16 + grp * 4 + r;
#pragma unroll
        for (int j = 0; j < 4; ++j)
            po[(size_t)(b * SS + row) * DD + h * DHH + j * 16 + l16] =
                f2b(accO[j][r] * inv);
        if (l16 == 0)
            scl[((size_t)half * MM + b * SS + row) * HH + h] = mr + __log2f(accS[r]);
    }
}

// ---------------------------------------------------------------------------
// Combine split-K halves: out = sum_i 2^(w_i - max_w) * O_i / sum_i 2^(...).
// In-place into part[0] (the wo-proj input). One block per row.
// ---------------------------------------------------------------------------
__global__ __launch_bounds__(256)
void attn_combine(unsigned short* __restrict__ part, const float* __restrict__ scl)
{
    const int row = blockIdx.x, tid = threadIdx.x;
    const int h = tid >> 4;                 // 4 cols per thread, within one head
    const float w0 = scl[(size_t)row * HH + h];
    const float w1 = scl[((size_t)MM + row) * HH + h];
    const float m  = fmaxf(w0, w1);
    float c0 = __builtin_amdgcn_exp2f(w0 - m);
    float c1 = __builtin_amdgcn_exp2f(w1 - m);
    const float d = 1.0f / (c0 + c1);
    c0 *= d; c1 *= d;
    ushort4* p0 = (ushort4*)part;
    const ushort4* p1 = (const ushort4*)(part + (size_t)MM * DD);
    const ushort4 a = p0[(size_t)row * 256 + tid];
    const ushort4 bb = p1[(size_t)row * 256 + tid];
    ushort4 o4;
    o4.x = f2b(c0 * b2f(a.x) + c1 * b2f(bb.x));
    o4.y = f2b(c0 * b2f(a.y) + c1 * b2f(bb.y));
    o4.z = f2b(c0 * b2f(a.z) + c1 * b2f(bb.z));
    o4.w = f2b(c0 * b2f(a.w) + c1 * b2f(bb.w));
    p0[(size_t)row * 256 + tid] = o4;
}

// ---------------------------------------------------------------------------
// LayerNorm D=1024. INBF: input bf16(1)/fp32(0). OUTBF: output bf16(1)/fp32(0).
// ---------------------------------------------------------------------------
template <int INBF, int OUTBF>
__global__ __launch_bounds__(256)
void ln_kernel(const void* __restrict__ xv, const float* __restrict__ g,
               const float* __restrict__ beta, void* __restrict__ outv)
{
    const int row = blockIdx.x;
    const int tid = threadIdx.x;
    float x0, x1, x2, x3;
    if (INBF) {
        const ushort4 xi = reinterpret_cast<const ushort4*>(xv)[(size_t)row * 256 + tid];
        x0 = b2f(xi.x); x1 = b2f(xi.y); x2 = b2f(xi.z); x3 = b2f(xi.w);
    } else {
        const float4 xi = reinterpret_cast<const float4*>(xv)[(size_t)row * 256 + tid];
        x0 = xi.x; x1 = xi.y; x2 = xi.z; x3 = xi.w;
    }
    float s  = x0 + x1 + x2 + x3;
    float sq = x0 * x0 + x1 * x1 + x2 * x2 + x3 * x3;
#pragma unroll
    for (int off = 1; off < 64; off <<= 1) {
        s  += __shfl_xor(s, off);
        sq += __shfl_xor(sq, off);
    }
    __shared__ float ssum[4], ssq[4];
    const int wid = tid >> 6;
    if ((tid & 63) == 0) { ssum[wid] = s; ssq[wid] = sq; }
    __syncthreads();
    s  = ssum[0] + ssum[1] + ssum[2] + ssum[3];
    sq = ssq[0]  + ssq[1]  + ssq[2]  + ssq[3];
    const float mean = s * (1.0f / DD);
    const float var  = fmaxf(sq * (1.0f / DD) - mean * mean, 0.0f);
    const float rstd = rsqrtf(var + 1e-5f);
    const float4 gv = reinterpret_cast<const float4*>(g)[tid];
    const float4 bv = reinterpret_cast<const float4*>(beta)[tid];
    float4 ov;
    ov.x = (x0 - mean) * rstd * gv.x + bv.x;
    ov.y = (x1 - mean) * rstd * gv.y + bv.y;
    ov.z = (x2 - mean) * rstd * gv.z + bv.z;
    ov.w = (x3 - mean) * rstd * gv.w + bv.w;
    if (OUTBF) {
        ushort4 o4;
        o4.x = f2b(ov.x); o4.y = f2b(ov.y); o4.z = f2b(ov.z); o4.w = f2b(ov.w);
        reinterpret_cast<ushort4*>(outv)[(size_t)row * 256 + tid] = o4;
    } else {
        reinterpret_cast<float4*>(outv)[(size_t)row * 256 + tid] = ov;
    }
}

// ---------------------------------------------------------------------------
extern "C" void kernel_launch(void* const* d_in, const int* in_sizes, int n_in,
                              void* d_out, int out_size, void* d_ws, size_t ws_size,
                              hipStream_t stream)
{
    (void)in_sizes; (void)n_in; (void)out_size; (void)ws_size;

    const float* x     = (const float*)d_in[0];
    const int*   mask  = (const int*)  d_in[1];
    const float* wq    = (const float*)d_in[2];
    const float* bq    = (const float*)d_in[3];
    const float* wk    = (const float*)d_in[4];
    const float* bk    = (const float*)d_in[5];
    const float* wv    = (const float*)d_in[6];
    const float* bv    = (const float*)d_in[7];
    const float* wo    = (const float*)d_in[8];
    const float* bo    = (const float*)d_in[9];
    const float* ln1_g = (const float*)d_in[10];
    const float* ln1_b = (const float*)d_in[11];
    const float* w1    = (const float*)d_in[12];
    const float* b1    = (const float*)d_in[13];
    const float* w2    = (const float*)d_in[14];
    const float* b2    = (const float*)d_in[15];
    const float* ln2_g = (const float*)d_in[16];
    const float* ln2_b = (const float*)d_in[17];

    float* out = (float*)d_out;
    char*  wsb = (char*)d_ws;
    const size_t MB = 1u << 20;

    unsigned short* wqkvT = (unsigned short*)(wsb + 0);        // [3072][1024]
    unsigned short* woT   = (unsigned short*)(wsb + 6 * MB);   // [1024][1024]
    unsigned short* w1T   = (unsigned short*)(wsb + 8 * MB);   // [2048][1024]
    unsigned short* w2T   = (unsigned short*)(wsb + 12 * MB);  // [1024][2048]
    float*          bqkv  = (float*)(wsb + 16 * MB);           // [3072]
    float*          sclb  = (float*)(wsb + 16 * MB + 32768);   // [2][4096][16]
    unsigned short* qkb   = (unsigned short*)(wsb + 17 * MB);  // [4096][2048]
    unsigned short* vtb   = (unsigned short*)(wsb + 33 * MB);  // [2*16*64][2048]
    unsigned short* xb    = (unsigned short*)(wsb + 41 * MB);  // [4096][1024]
    unsigned short* partb = xb;                                // [2][4096][1024]:
                                                               // half0 41-49 (xb dead),
                                                               // half1 49-57 (f1b area)
    unsigned short* ab16  = xb;                                // combined attn out
    unsigned short* t0    = (unsigned short*)(wsb + 17 * MB);  // bf16, qkb dead
    unsigned short* hb16  = (unsigned short*)(wsb + 33 * MB);  // vtb dead
    unsigned short* f1b   = (unsigned short*)(wsb + 41 * MB + 8 * MB); // [4096][2048] (49..65)? no:
    f1b = (unsigned short*)(wsb + 41 * MB);                    // reuse 41-57 after combine?  —
    // NOTE: f1b (41..57) would overwrite ab16 (41..49) which wo-proj still reads.
    // Keep FFN1 output in the qkb/t0-free区? t0 occupies 17..25 (bf16 [4096][1024] = 8MB).
    // Place f1b at 57..73 MB?  ws_size unknown — instead put f1b at 25..41 MB
    // (t0 uses 17..25; hb16 moves to 33..41 would clash).  Final safe layout below.
    f1b = (unsigned short*)(wsb + 49 * MB);                    // [4096][2048] bf16 = 16MB (49..65)?
    // part half1 (49..57) is dead after combine; FFN1 runs after combine. 49..65 OK
    // only if ws >= 65MB; previous peak was 57MB. To stay <=57MB, overlay f1b on
    // 41..57 but ab16 (41..49) is read by wo-proj BEFORE FFN1 writes f1b — the
    // launch ORDER makes this safe: wo-proj completes before FFN1 starts.
    f1b = (unsigned short*)(wsb + 41 * MB);                    // [4096][2048] (41..57)
    unsigned short* t1    = (unsigned short*)(wsb + 17 * MB);  // bf16, t0 dead

    // fused prep: x->bf16, 6 transposes, bias pack
    prep<<<6156, 256, 0, stream>>>(x, wq, wk, wv, wo, w1, w2, bq, bk, bv,
                                   xb, wqkvT, woT, w1T, w2T, bqkv);
    // fused QKV projection: q|k -> qkb, v -> vtb transposed per head
    mgemm<0, 0, 0, 1, 128><<<dim3(24, 32), 256, 0, stream>>>(
        xb, wqkvT, bqkv, nullptr, qkb, vtb, MM, 3 * DD, DD, 2048);
    // flash attention, split-K over 2 halves (grid z = b*2+half)
    attn_mfma<<<dim3(SS / 128, HH, BB * 2), 512, 0, stream>>>(
        qkb, vtb, mask, partb, sclb);
    // combine halves -> ab16 (in-place over part half 0)
    attn_combine<<<MM, 256, 0, stream>>>(partb, sclb);
    // output projection + residual x -> t0 (bf16), BN=64 grid 512
    mgemm<0, 1, 0, 0, 64><<<dim3(16, 32), 256, 0, stream>>>(
        ab16, woT, bo, x, t0, nullptr, MM, DD, DD, DD);
    // LN1 (bf16 in) -> bf16
    ln_kernel<1, 1><<<MM, 256, 0, stream>>>(t0, ln1_g, ln1_b, hb16);
    // FFN1 (BN=128 grid 512) — writes f1b (41..57), after wo-proj read ab16
    mgemm<1, 0, 0, 0, 128><<<dim3(16, 32), 256, 0, stream>>>(
        hb16, w1T, b1, nullptr, f1b, nullptr, MM, 2 * DD, DD, 2 * DD);
    // FFN2 + residual hb16 -> t1 (bf16), BN=64 grid 512
    mgemm<0, 2, 0, 0, 64><<<dim3(16, 32), 256, 0, stream>>>(
        f1b, w2T, b2, hb16, t1, nullptr, MM, DD, 2 * DD, DD);
    // LN2 (bf16 in) -> fp32 out
    ln_kernel<1, 0><<<MM, 256, 0, stream>>>(t1, ln2_g, ln2_b, out);
}

// Round 15
// 223.319 us; speedup vs baseline: 1.0687x; 1.0687x over previous
//
#include <hip/hip_runtime.h>
#include <math.h>

#define BB  2
#define SS  2048
#define DD  1024
#define HH  16
#define DHH 64
#define MM  (BB * SS)   // 4096 rows

typedef float f32x4 __attribute__((ext_vector_type(4)));
typedef short s16x8 __attribute__((ext_vector_type(8)));

__device__ __forceinline__ unsigned short f2b(float f) {
    union { float f; unsigned u; } v; v.f = f;
    unsigned r = v.u + 0x7fffu + ((v.u >> 16) & 1u);
    return (unsigned short)(r >> 16);
}
__device__ __forceinline__ float b2f(unsigned short u) {
    union { unsigned u; float f; } v; v.u = ((unsigned)u) << 16;
    return v.f;
}
// pack 2 f32 -> 2 bf16 (low=first), RNE
__device__ __forceinline__ unsigned cvtpk(float lo, float hi) {
    unsigned r;
    asm("v_cvt_pk_bf16_f32 %0, %1, %2" : "=v"(r) : "v"(lo), "v"(hi));
    return r;
}

typedef __attribute__((address_space(1))) void gv_t;
typedef __attribute__((address_space(3))) void lv_t;
__device__ __forceinline__ void gld16(const void* g, void* l) {
    __builtin_amdgcn_global_load_lds((gv_t*)(void*)g, (lv_t*)l, 16, 0, 0);
}

__device__ __forceinline__ int sigma(int row) { return (row + (row >> 3)) & 7; }
// 64-col bf16 tile swizzle (16B-chunk XOR)
__device__ __forceinline__ int sidx(int row, int col) {
    return row * 64 + (col ^ (sigma(row) << 3));
}

// ---------------------------------------------------------------------------
// bf16 MFMA GEMM (m97 structure, 16x16x32 core — round-7-verified):
// C = A @ B^T + bias (+res)(relu).  Tile 128 x BN (BN = 128 or 64).
// BN=64 doubles the grid -> more blocks/CU to overlap the per-K-step drain.
// VS=1: QKV mode — cols<2048 -> out, cols>=2048 -> vt[b][h][dh][s].
// RES: 0 none, 1 fp32, 2 bf16.  OUTF: 1 fp32 out, 0 bf16 out.
// ---------------------------------------------------------------------------
template <int RELU, int RES, int OUTF, int VS, int BN>
__global__ __launch_bounds__(256)
void mgemm(const unsigned short* __restrict__ A, const unsigned short* __restrict__ B,
           const float* __restrict__ bias, const void* __restrict__ res,
           void* __restrict__ out, unsigned short* __restrict__ vt,
           int M, int N, int K, int outN)
{
    __shared__ short As[128 * 64];
    __shared__ short Bs[BN * 64];

    const int tid  = threadIdx.x;
    const int wave = tid >> 6, lane = tid & 63;
    const int bm = blockIdx.y * 128, bn = blockIdx.x * BN;
    const int srow = tid >> 3;
    const int scol = (tid & 7) * 8;
    const int fr = lane & 15;
    const int fk = (lane >> 4) * 8;
    const int wrow = (BN == 128) ? (wave >> 1) * 64 : wave * 32;
    const int wcol = (BN == 128) ? (wave & 1) * 64 : 0;
    constexpr int MI = (BN == 128) ? 4 : 2;   // m-frags per wave

    f32x4 acc[MI][4];
#pragma unroll
    for (int i = 0; i < MI; ++i)
#pragma unroll
        for (int j = 0; j < 4; ++j) acc[i][j] = (f32x4){0.f, 0.f, 0.f, 0.f};

    for (int k0 = 0; k0 < K; k0 += 64) {
#pragma unroll
        for (int it = 0; it < 4; ++it)
            gld16(&A[(size_t)(bm + it * 32 + srow) * K + k0 + scol],
                  &As[it * 2048 + wave * 512]);
#pragma unroll
        for (int it = 0; it < BN / 32; ++it)
            gld16(&B[(size_t)(bn + it * 32 + srow) * K + k0 + scol],
                  &Bs[it * 2048 + wave * 512]);
        __syncthreads();

#pragma unroll
        for (int kk = 0; kk < 2; ++kk) {
            s16x8 af[MI], bf[4];
#pragma unroll
            for (int i = 0; i < MI; ++i)
                af[i] = *(const s16x8*)&As[(wrow + i * 16 + fr) * 64 + kk * 32 + fk];
#pragma unroll
            for (int j = 0; j < 4; ++j)
                bf[j] = *(const s16x8*)&Bs[(wcol + j * 16 + fr) * 64 + kk * 32 + fk];
#pragma unroll
            for (int i = 0; i < MI; ++i)
#pragma unroll
                for (int j = 0; j < 4; ++j)
                    acc[i][j] = __builtin_amdgcn_mfma_f32_16x16x32_bf16(
                        af[i], bf[j], acc[i][j], 0, 0, 0);
        }
        __syncthreads();
    }

    const int r0 = bm + wrow + (lane >> 4) * 4;
    const int c0 = bn + wcol + (lane & 15);
    const float* resf          = (const float*)res;
    const unsigned short* resh = (const unsigned short*)res;
    float* outf          = (float*)out;
    unsigned short* outh = (unsigned short*)out;

    if (VS == 1 && bn >= 2048) {
#pragma unroll
        for (int i = 0; i < MI; ++i)
#pragma unroll
            for (int j = 0; j < 4; ++j) {
                const int col = c0 + j * 16;
                const int hh = (col >> 6) & 15, dh = col & 63;
                const float bcol = bias[col];
#pragma unroll
                for (int r = 0; r < 4; ++r) {
                    const int row = r0 + i * 16 + r;
                    const int bb = row >> 11, s = row & 2047;
                    vt[(size_t)(((bb * 16 + hh) * 64) + dh) * 2048 + s] =
                        f2b(acc[i][j][r] + bcol);
                }
            }
        return;
    }

#pragma unroll
    for (int i = 0; i < MI; ++i)
#pragma unroll
        for (int j = 0; j < 4; ++j) {
            const int col = c0 + j * 16;
            const float bcol = bias[col];
#pragma unroll
            for (int r = 0; r < 4; ++r) {
                const int row = r0 + i * 16 + r;
                float v = acc[i][j][r] + bcol;
                if (RES == 1) v += resf[(size_t)row * outN + col];
                if (RES == 2) v += b2f(resh[(size_t)row * outN + col]);
                if (RELU)     v = fmaxf(v, 0.f);
                if (OUTF) outf[(size_t)row * outN + col] = v;
                else      outh[(size_t)row * outN + col] = f2b(v);
            }
        }
}

// ---------------------------------------------------------------------------
// Fused prep: x->bf16, 6 weight transposes (fp32[K][N] -> bf16[N][K]), bias pack.
// ---------------------------------------------------------------------------
__global__ __launch_bounds__(256)
void prep(const float* __restrict__ x,
          const float* __restrict__ wq, const float* __restrict__ wk,
          const float* __restrict__ wv, const float* __restrict__ wo,
          const float* __restrict__ w1, const float* __restrict__ w2,
          const float* __restrict__ bq, const float* __restrict__ bk,
          const float* __restrict__ bv,
          unsigned short* __restrict__ xb, unsigned short* __restrict__ wqkvT,
          unsigned short* __restrict__ woT, unsigned short* __restrict__ w1T,
          unsigned short* __restrict__ w2T, float* __restrict__ bqkv)
{
    __shared__ float T[64][65];
    const int tid = threadIdx.x;
    int bid = blockIdx.x;

    if (bid < 4096) {   // x -> bf16
        const int i = bid * 256 + tid;
        const float4 v = ((const float4*)x)[i];
        ushort4 o4;
        o4.x = f2b(v.x); o4.y = f2b(v.y); o4.z = f2b(v.z); o4.w = f2b(v.w);
        ((ushort4*)xb)[i] = o4;
        return;
    }
    bid -= 4096;

    if (bid >= 2048) {  // bias pack, 12 blocks
        const int i = (bid - 2048) * 256 + tid;
        if (i < 1024) bqkv[i] = bq[i];
        else if (i < 2048) bqkv[i] = bk[i - 1024];
        else if (i < 3072) bqkv[i] = bv[i - 2048];
        return;
    }

    const float* src; unsigned short* dst; int K, N, nbx, sub;
    if (bid < 256)       { src = wq; dst = wqkvT;               K = 1024; N = 1024; nbx = 16; sub = bid; }
    else if (bid < 512)  { src = wk; dst = wqkvT + 1024 * 1024; K = 1024; N = 1024; nbx = 16; sub = bid - 256; }
    else if (bid < 768)  { src = wv; dst = wqkvT + 2048 * 1024; K = 1024; N = 1024; nbx = 16; sub = bid - 512; }
    else if (bid < 1024) { src = wo; dst = woT;                 K = 1024; N = 1024; nbx = 16; sub = bid - 768; }
    else if (bid < 1536) { src = w1; dst = w1T;                 K = 1024; N = 2048; nbx = 32; sub = bid - 1024; }
    else                 { src = w2; dst = w2T;                 K = 2048; N = 1024; nbx = 16; sub = bid - 1536; }

    const int n0 = (sub % nbx) * 64, k0 = (sub / nbx) * 64;
    const int c = tid & 63, rb = tid >> 6;
#pragma unroll
    for (int it = 0; it < 16; ++it) {
        const int r = it * 4 + rb;
        T[r][c] = src[(size_t)(k0 + r) * N + n0 + c];
    }
    __syncthreads();
#pragma unroll
    for (int it = 0; it < 16; ++it) {
        const int r = it * 4 + rb;
        dst[(size_t)(n0 + r) * K + k0 + c] = f2b(T[c][r]);
    }
}

// ---------------------------------------------------------------------------
// MFMA flash attention (round-7-verified, FROZEN): QBLK=128, KVBLK=64,
// swapped QK^T, lane-local softmax, cvt_pk P pack into dead-Q LDS,
// two barriers per tile. qk: [B*S][2048] = [q|k]; vt: [B][H][64][2048].
// ---------------------------------------------------------------------------
__global__ __launch_bounds__(512)
void attn_mfma(const unsigned short* __restrict__ qk,
               const unsigned short* __restrict__ vt,
               const int* __restrict__ mask, unsigned short* __restrict__ o)
{
    const int b = blockIdx.z, h = blockIdx.y, q0 = blockIdx.x * 128;
    __shared__ unsigned short QP[8192];   // 128x64 Q; after frag load: P strips
    __shared__ unsigned short Ks[4096];   // 64x64
    __shared__ unsigned short Vs[4096];   // 64x64 (rows=dh, cols=kv)
    __shared__ float maskf[64];
    const int tid = threadIdx.x, wave = tid >> 6, lane = tid & 63;
    const int grp = lane >> 4, l16 = lane & 15;

    const size_t qkbase = (size_t)(b * SS) * 2048 + h * DHH;
    const size_t vbase  = (size_t)((b * HH + h) * 64) * 2048;
    const float SC = 0.18033688f;          // 0.125 * log2(e)
    const float MNEG = -1.442695e9f;       // -1e9 * log2(e)

    // ---- stage Q (once) ----
#pragma unroll
    for (int it = 0; it < 2; ++it) {
        const int slot = it * 512 + tid;
        const int row = slot >> 3, dhb = slot & 7;
        const int src = (dhb ^ sigma(row)) * 8;
        gld16(&qk[qkbase + (size_t)(q0 + row) * 2048 + src],
              &QP[it * 4096 + wave * 512]);
    }
    const int krow = tid >> 3, kdhb = tid & 7;
    const int ksrc = (kdhb ^ sigma(krow)) * 8;
    __syncthreads();
    const int prow = wave * 16 + l16;     // this lane's q row (LDS row index)
    const s16x8 aq0 = *(const s16x8*)&QP[sidx(prow, grp * 8)];
    const s16x8 aq1 = *(const s16x8*)&QP[sidx(prow, 32 + grp * 8)];
    // QP strip [wave*1024 ..) is now reused for P (wave-local, lgkm-ordered)

    const s16x8 ones = {(short)0x3F80, (short)0x3F80, (short)0x3F80, (short)0x3F80,
                        (short)0x3F80, (short)0x3F80, (short)0x3F80, (short)0x3F80};

    f32x4 accO[4];
#pragma unroll
    for (int j = 0; j < 4; ++j) accO[j] = (f32x4){0.f, 0.f, 0.f, 0.f};
    f32x4 accS = (f32x4){0.f, 0.f, 0.f, 0.f};
    float mrow = -1e30f;                   // running max for q = l16 (scalar)

    for (int kt = 0; kt < SS / 64; ++kt) {
        const int kv0 = kt * 64;
        __syncthreads();   // prev tile reads done
        gld16(&qk[qkbase + (size_t)(kv0 + krow) * 2048 + 1024 + ksrc], &Ks[wave * 512]);
        gld16(&vt[vbase + (size_t)krow * 2048 + kv0 + ksrc],           &Vs[wave * 512]);
        if (tid < 64) maskf[tid] = mask[b * SS + kv0 + tid] ? 0.f : MNEG;
        __syncthreads();   // staging + maskf visible

        // ---- QK^T (swapped: K is A, Q is B) ----
        f32x4 sv[4];
        __builtin_amdgcn_s_setprio(1);
#pragma unroll
        for (int j = 0; j < 4; ++j) {
            const s16x8 bk0 = *(const s16x8*)&Ks[sidx(j * 16 + l16, grp * 8)];
            const s16x8 bk1 = *(const s16x8*)&Ks[sidx(j * 16 + l16, 32 + grp * 8)];
            f32x4 z = (f32x4){0.f, 0.f, 0.f, 0.f};
            z = __builtin_amdgcn_mfma_f32_16x16x32_bf16(bk0, aq0, z, 0, 0, 0);
            z = __builtin_amdgcn_mfma_f32_16x16x32_bf16(bk1, aq1, z, 0, 0, 0);
            sv[j] = z;   // sv[j][r] = S[q=l16][k = j*16 + grp*4 + r]
        }
        __builtin_amdgcn_s_setprio(0);
#pragma unroll
        for (int j = 0; j < 4; ++j) {
            const float4 mv = *(const float4*)&maskf[j * 16 + grp * 4];
            sv[j][0] = sv[j][0] * SC + mv.x;
            sv[j][1] = sv[j][1] * SC + mv.y;
            sv[j][2] = sv[j][2] * SC + mv.z;
            sv[j][3] = sv[j][3] * SC + mv.w;
        }

        // ---- softmax for q=l16: lane-local max + 2 shfl ----
        float mx = -1e30f;
#pragma unroll
        for (int j = 0; j < 4; ++j)
#pragma unroll
            for (int r = 0; r < 4; ++r) mx = fmaxf(mx, sv[j][r]);
        mx = fmaxf(mx, __shfl_xor(mx, 16));
        mx = fmaxf(mx, __shfl_xor(mx, 32));

        if (!__all(mx <= mrow + 8.f)) {
            const float mnew = fmaxf(mrow, mx);
            const float corrq = __builtin_amdgcn_exp2f(mrow - mnew);  // for q=l16
            mrow = mnew;
            float cr[4];   // corr for q = grp*4+r (PV accumulator layout)
#pragma unroll
            for (int r = 0; r < 4; ++r) cr[r] = __shfl(corrq, grp * 4 + r);
#pragma unroll
            for (int r = 0; r < 4; ++r) {
                accS[r] *= cr[r];
#pragma unroll
                for (int j = 0; j < 4; ++j) accO[j][r] *= cr[r];
            }
        }

        // ---- P = exp2, pack to bf16, write wave-private strip ----
#pragma unroll
        for (int j = 0; j < 4; ++j) {
            const float p0 = __builtin_amdgcn_exp2f(sv[j][0] - mrow);
            const float p1 = __builtin_amdgcn_exp2f(sv[j][1] - mrow);
            const float p2 = __builtin_amdgcn_exp2f(sv[j][2] - mrow);
            const float p3 = __builtin_amdgcn_exp2f(sv[j][3] - mrow);
            *(unsigned*)&QP[sidx(prow, j * 16 + grp * 4)]     = cvtpk(p0, p1);
            *(unsigned*)&QP[sidx(prow, j * 16 + grp * 4 + 2)] = cvtpk(p2, p3);
        }

        // ---- PV + ones row-sum ----
        const s16x8 pa0 = *(const s16x8*)&QP[sidx(prow, grp * 8)];
        const s16x8 pa1 = *(const s16x8*)&QP[sidx(prow, 32 + grp * 8)];
        __builtin_amdgcn_s_setprio(1);
        accS = __builtin_amdgcn_mfma_f32_16x16x32_bf16(pa0, ones, accS, 0, 0, 0);
        accS = __builtin_amdgcn_mfma_f32_16x16x32_bf16(pa1, ones, accS, 0, 0, 0);
#pragma unroll
        for (int j = 0; j < 4; ++j) {
            const s16x8 vb0 = *(const s16x8*)&Vs[sidx(j * 16 + l16, grp * 8)];
            const s16x8 vb1 = *(const s16x8*)&Vs[sidx(j * 16 + l16, 32 + grp * 8)];
            accO[j] = __builtin_amdgcn_mfma_f32_16x16x32_bf16(pa0, vb0, accO[j], 0, 0, 0);
            accO[j] = __builtin_amdgcn_mfma_f32_16x16x32_bf16(pa1, vb1, accO[j], 0, 0, 0);
        }
        __builtin_amdgcn_s_setprio(0);
    }

    // ---- epilogue (accO/accS rows: q = grp*4+r; cols: dh = j*16+l16) ----
#pragma unroll
    for (int r = 0; r < 4; ++r) {
        const float inv = 1.0f / accS[r];
        const int row = q0 + wave * 16 + grp * 4 + r;
#pragma unroll
        for (int j = 0; j < 4; ++j)
            o[(size_t)(b * SS + row) * DD + h * DHH + j * 16 + l16] =
                f2b(accO[j][r] * inv);
    }
}

// ---------------------------------------------------------------------------
// LayerNorm D=1024. INBF: input bf16(1)/fp32(0). OUTBF: output bf16(1)/fp32(0).
// ---------------------------------------------------------------------------
template <int INBF, int OUTBF>
__global__ __launch_bounds__(256)
void ln_kernel(const void* __restrict__ xv, const float* __restrict__ g,
               const float* __restrict__ beta, void* __restrict__ outv)
{
    const int row = blockIdx.x;
    const int tid = threadIdx.x;
    float x0, x1, x2, x3;
    if (INBF) {
        const ushort4 xi = reinterpret_cast<const ushort4*>(xv)[(size_t)row * 256 + tid];
        x0 = b2f(xi.x); x1 = b2f(xi.y); x2 = b2f(xi.z); x3 = b2f(xi.w);
    } else {
        const float4 xi = reinterpret_cast<const float4*>(xv)[(size_t)row * 256 + tid];
        x0 = xi.x; x1 = xi.y; x2 = xi.z; x3 = xi.w;
    }
    float s  = x0 + x1 + x2 + x3;
    float sq = x0 * x0 + x1 * x1 + x2 * x2 + x3 * x3;
#pragma unroll
    for (int off = 1; off < 64; off <<= 1) {
        s  += __shfl_xor(s, off);
        sq += __shfl_xor(sq, off);
    }
    __shared__ float ssum[4], ssq[4];
    const int wid = tid >> 6;
    if ((tid & 63) == 0) { ssum[wid] = s; ssq[wid] = sq; }
    __syncthreads();
    s  = ssum[0] + ssum[1] + ssum[2] + ssum[3];
    sq = ssq[0]  + ssq[1]  + ssq[2]  + ssq[3];
    const float mean = s * (1.0f / DD);
    const float var  = fmaxf(sq * (1.0f / DD) - mean * mean, 0.0f);
    const float rstd = rsqrtf(var + 1e-5f);
    const float4 gv = reinterpret_cast<const float4*>(g)[tid];
    const float4 bv = reinterpret_cast<const float4*>(beta)[tid];
    float4 ov;
    ov.x = (x0 - mean) * rstd * gv.x + bv.x;
    ov.y = (x1 - mean) * rstd * gv.y + bv.y;
    ov.z = (x2 - mean) * rstd * gv.z + bv.z;
    ov.w = (x3 - mean) * rstd * gv.w + bv.w;
    if (OUTBF) {
        ushort4 o4;
        o4.x = f2b(ov.x); o4.y = f2b(ov.y); o4.z = f2b(ov.z); o4.w = f2b(ov.w);
        reinterpret_cast<ushort4*>(outv)[(size_t)row * 256 + tid] = o4;
    } else {
        reinterpret_cast<float4*>(outv)[(size_t)row * 256 + tid] = ov;
    }
}

// ---------------------------------------------------------------------------
extern "C" void kernel_launch(void* const* d_in, const int* in_sizes, int n_in,
                              void* d_out, int out_size, void* d_ws, size_t ws_size,
                              hipStream_t stream)
{
    (void)in_sizes; (void)n_in; (void)out_size; (void)ws_size;

    const float* x     = (const float*)d_in[0];
    const int*   mask  = (const int*)  d_in[1];
    const float* wq    = (const float*)d_in[2];
    const float* bq    = (const float*)d_in[3];
    const float* wk    = (const float*)d_in[4];
    const float* bk    = (const float*)d_in[5];
    const float* wv    = (const float*)d_in[6];
    const float* bv    = (const float*)d_in[7];
    const float* wo    = (const float*)d_in[8];
    const float* bo    = (const float*)d_in[9];
    const float* ln1_g = (const float*)d_in[10];
    const float* ln1_b = (const float*)d_in[11];
    const float* w1    = (const float*)d_in[12];
    const float* b1    = (const float*)d_in[13];
    const float* w2    = (const float*)d_in[14];
    const float* b2    = (const float*)d_in[15];
    const float* ln2_g = (const float*)d_in[16];
    const float* ln2_b = (const float*)d_in[17];

    float* out = (float*)d_out;
    char*  wsb = (char*)d_ws;
    const size_t MB = 1u << 20;

    unsigned short* wqkvT = (unsigned short*)(wsb + 0);        // [3072][1024]
    unsigned short* woT   = (unsigned short*)(wsb + 6 * MB);   // [1024][1024]
    unsigned short* w1T   = (unsigned short*)(wsb + 8 * MB);   // [2048][1024]
    unsigned short* w2T   = (unsigned short*)(wsb + 12 * MB);  // [1024][2048]
    float*          bqkv  = (float*)(wsb + 16 * MB);           // [3072]
    unsigned short* qkb   = (unsigned short*)(wsb + 17 * MB);  // [4096][2048]
    unsigned short* vtb   = (unsigned short*)(wsb + 33 * MB);  // [2*16*64][2048]
    unsigned short* xb    = (unsigned short*)(wsb + 41 * MB);  // [4096][1024]
    unsigned short* ab16  = xb;                                // attn out reuses xb
    unsigned short* t0    = (unsigned short*)(wsb + 17 * MB);  // bf16, qkb dead
    unsigned short* hb16  = (unsigned short*)(wsb + 33 * MB);  // vtb dead
    unsigned short* f1b   = (unsigned short*)(wsb + 41 * MB);  // [4096][2048]
    unsigned short* t1    = (unsigned short*)(wsb + 17 * MB);  // bf16, t0 dead

    // fused prep: x->bf16, 6 transposes, bias pack
    prep<<<6156, 256, 0, stream>>>(x, wq, wk, wv, wo, w1, w2, bq, bk, bv,
                                   xb, wqkvT, woT, w1T, w2T, bqkv);
    // fused QKV projection: q|k -> qkb, v -> vtb transposed per head.
    // BN=64: grid 48x32 = 1536 blocks (6/CU) for drain overlap.
    mgemm<0, 0, 0, 1, 64><<<dim3(48, 32), 256, 0, stream>>>(
        xb, wqkvT, bqkv, nullptr, qkb, vtb, MM, 3 * DD, DD, 2048);
    // flash attention (frozen r7 structure)
    attn_mfma<<<dim3(SS / 128, HH, BB), 512, 0, stream>>>(qkb, vtb, mask, ab16);
    // output projection + residual x -> t0 (bf16), BN=64 grid 512
    mgemm<0, 1, 0, 0, 64><<<dim3(16, 32), 256, 0, stream>>>(
        ab16, woT, bo, x, t0, nullptr, MM, DD, DD, DD);
    // LN1 (bf16 in) -> bf16
    ln_kernel<1, 1><<<MM, 256, 0, stream>>>(t0, ln1_g, ln1_b, hb16);
    // FFN1, BN=64: grid 32x32 = 1024 blocks (4/CU)
    mgemm<1, 0, 0, 0, 64><<<dim3(32, 32), 256, 0, stream>>>(
        hb16, w1T, b1, nullptr, f1b, nullptr, MM, 2 * DD, DD, 2 * DD);
    // FFN2 + residual hb16 -> t1 (bf16), BN=64 grid 512
    mgemm<0, 2, 0, 0, 64><<<dim3(16, 32), 256, 0, stream>>>(
        f1b, w2T, b2, hb16, t1, nullptr, MM, DD, 2 * DD, DD);
    // LN2 (bf16 in) -> fp32 out
    ln_kernel<1, 0><<<MM, 256, 0, stream>>>(t1, ln2_g, ln2_b, out);
}